// Round 9
// baseline (1886.356 us; speedup 1.0000x reference)
//
#include <hip/hip_runtime.h>
#include <math.h>

#define NEGINF (-INFINITY)
constexpr int Np = 4096;
constexpr int Kn = 20;
constexpr float EPSf = 1e-5f;
constexpr float SLOPE = 0.2f;

typedef __bf16 bf16x8 __attribute__((ext_vector_type(8)));
typedef float f32x4 __attribute__((ext_vector_type(4)));
typedef unsigned long long ull;
typedef unsigned int u32;

// ---------------- K1: knn1 + edgeconv1 fused ----------------
// grid (64, B), 256 thr, plain launch_bounds (round-6-proven: no scratch storm).
__global__ __launch_bounds__(256) void k1_knn1_edge1(
    const float* __restrict__ x, const float* __restrict__ W1,
    const float* __restrict__ g1, const float* __restrict__ b1,
    const float* __restrict__ m1, const float* __restrict__ v1,
    float* __restrict__ x1, __bf16* __restrict__ x1h, __bf16* __restrict__ x1l,
    float* __restrict__ xx2)
{
  __shared__ ull smem[6144];   // 48 KB: pbuf[24][256] ph1; dump[4][64][20]+midx ph2/3

  const int b = blockIdx.y;
  const int n0 = blockIdx.x * 64;
  const int tid = threadIdx.x;
  const int w = tid >> 6, L = tid & 63;
  const float* __restrict__ xr = x + (size_t)b*2*Np;
  const float* __restrict__ yr = xr + Np;

  const int n = n0 + L;
  const float px = xr[n], py = yr[n];

  ull kv[20];
#pragma unroll
  for (int s = 0; s < 20; ++s) kv[s] = 0ull;
  u32 u_cut = 0xFFFFFFFFu;
  int cnt = 0;

  auto flushK = [&]() {
#pragma unroll 1
    for (int f0 = 0; f0 < 24; f0 += 8) {
      if (__all(f0 >= cnt)) break;
      ull t0[8];
#pragma unroll
      for (int u = 0; u < 8; ++u) t0[u] = smem[(f0+u)*256 + tid];
#pragma unroll
      for (int u = 0; u < 8; ++u) {        // static t0 index (fully unrolled)
        int f = f0 + u;
        ull key = t0[u];
        if (f < cnt && key > kv[19]) {
          ull ck = key;
#pragma unroll
          for (int s = 0; s < 20; ++s) {
            bool sw = ck > kv[s];
            ull tv = kv[s];
            kv[s] = sw ? ck : kv[s];
            ck = sw ? tv : ck;
          }
        }
      }
    }
    cnt = 0;
    u_cut = ~(u32)(kv[19] >> 32);
  };

  const int base = w * 1024;
  for (int j0 = base; j0 < base + 1024; j0 += 16) {
#pragma unroll
    for (int c = 0; c < 4; ++c) {
      float4 xv = *reinterpret_cast<const float4*>(xr + j0 + c*4);  // uniform -> s_load
      float4 yv = *reinterpret_cast<const float4*>(yr + j0 + c*4);
      const float xs[4] = {xv.x, xv.y, xv.z, xv.w};
      const float ys[4] = {yv.x, yv.y, yv.z, yv.w};
#pragma unroll
      for (int r = 0; r < 4; ++r) {
        float dx = xs[r] - px, dy = ys[r] - py;
        float s = dx*dx + dy*dy;
        u32 ub = __float_as_uint(s);
        if (ub <= u_cut) {
          int j = j0 + c*4 + r;
          smem[cnt*256 + tid] = (((ull)~ub) << 32) | (u32)~(u32)j;
          ++cnt;
        }
      }
    }
    if (__any(cnt >= 8)) flushK();
  }
  flushK();

  __syncthreads();             // pbuf dead; switch to dump layout
#pragma unroll
  for (int k = 0; k < Kn; ++k) smem[((size_t)w*64 + L)*20 + k] = kv[k];
  __syncthreads();

  u32* midx = (u32*)(smem + 5120);   // 64 x 20 merged indices (disjoint region)
  if (tid < 64) {
    const int p = tid;
    ull h[4]; int pc[4];
#pragma unroll
    for (int q = 0; q < 4; ++q) { h[q] = smem[((size_t)q*64 + p)*20]; pc[q] = 0; }
#pragma unroll
    for (int k = 0; k < Kn; ++k) {
      ull best = h[0]; int sel = 0;
      if (h[1] > best) { best = h[1]; sel = 1; }
      if (h[2] > best) { best = h[2]; sel = 2; }
      if (h[3] > best) { best = h[3]; sel = 3; }
      midx[p*20 + k] = (u32)~(u32)best;
      int np_ = ++pc[sel];
      h[sel] = (np_ < 20) ? smem[((size_t)sel*64 + p)*20 + np_] : 0ull;
    }
  }
  __syncthreads();

  // phase 3: edgeconv1 — wave w handles points w*16 .. w*16+15, lane = channel o
  const int o = L;
  const float4 w1v = reinterpret_cast<const float4*>(W1)[o];
  const float sc = g1[o] / sqrtf(v1[o] + EPSf);
  const float mo = m1[o], bo = b1[o];

  for (int pi = 0; pi < 16; ++pi) {
    const int p = w*16 + pi;
    const int np = n0 + p;
    const float cx0 = xr[np], cx1 = yr[np];          // uniform
    const float cterm = (w1v.z - w1v.x)*cx0 + (w1v.w - w1v.y)*cx1;
    float xm = NEGINF;
#pragma unroll
    for (int k = 0; k < Kn; ++k) {
      int j = __builtin_amdgcn_readfirstlane(midx[p*20 + k]);
      float xj = xr[j], yj = yr[j];                  // s_loads
      float vv = w1v.x*xj + w1v.y*yj + cterm;
      float h = (vv - mo)*sc + bo;
      h = h >= 0.f ? h : SLOPE*h;
      xm = fmaxf(xm, h);
    }
    x1[(b*64 + o)*Np + np] = xm;
    __bf16 hb = (__bf16)xm;
    __bf16 lb = (__bf16)(xm - (float)hb);
    size_t tbase = ((size_t)b*Np + np)*64 + o;
    x1h[tbase] = hb;
    x1l[tbase] = lb;
    float s = xm*xm;
#pragma unroll
    for (int off = 1; off < 64; off <<= 1) s += __shfl_xor(s, off);
    if (L == 0) xx2[b*Np + np] = s;
  }
}

// ---------------- K2: knn2 — MFMA gram, pipelined subtiles, static-index flush ----------
// grid (256 rowblocks, B), 256 thr. Block: 16 rows x 4096 cols; wave w takes tiles tt==w mod 4.
// Subtile u (0..63): tile tt = w + (u>>2)*4, 16 cols at col16 = tt*64 + (u&3)*16.
// D[n=L15 -> row][m=quad*4+r -> col]; lane owns one row (n0+L15).
// Key = (sortable(e)<<32) | ~j, e = 2*dot - ||x_j||^2.
__global__ __launch_bounds__(256) void k2_knn2(
    const __bf16* __restrict__ xh, const __bf16* __restrict__ xl,
    const float* __restrict__ xx2, int* __restrict__ idx2)
{
  __shared__ ull smem[5120];   // 40 KB. ph1: sxx float[4096] @0 + pbuf[10][256] @2048
                               // ph2: dump[4][64][20] @0 ; ph3: stage1 out [0..1280)
  float* sxx = (float*)smem;
  ull* pbuf = smem + 2048;

  const int b = blockIdx.y;
  const int n0 = blockIdx.x * 16;
  const int tid = threadIdx.x;
  const int w = tid >> 6, L = tid & 63;
  const int L15 = L & 15, quad = L >> 4;

  for (int j = tid*4; j < Np; j += 1024)
    *reinterpret_cast<float4*>(&sxx[j]) = *reinterpret_cast<const float4*>(&xx2[(size_t)b*Np + j]);

  // B operand: rows n0..n0+15
  const __bf16* Rh = xh + ((size_t)b*Np + n0)*64;
  const __bf16* Rl = xl + ((size_t)b*Np + n0)*64;
  bf16x8 rh0 = *reinterpret_cast<const bf16x8*>(Rh + L15*64 +  0 + quad*8);
  bf16x8 rh1 = *reinterpret_cast<const bf16x8*>(Rh + L15*64 + 32 + quad*8);
  bf16x8 rl0 = *reinterpret_cast<const bf16x8*>(Rl + L15*64 +  0 + quad*8);
  bf16x8 rl1 = *reinterpret_cast<const bf16x8*>(Rl + L15*64 + 32 + quad*8);

  const __bf16* Cbh = xh + (size_t)b*Np*64;
  const __bf16* Cbl = xl + (size_t)b*Np*64;

  ull kv[20];
#pragma unroll
  for (int s = 0; s < 20; ++s) kv[s] = 0ull;
  float fthresh = NEGINF;
  int cnt = 0;

  __syncthreads();   // sxx ready

  auto insert5 = [&](int f0) {
#pragma unroll
    for (int u = 0; u < 5; ++u) {          // fully unrolled: all indices static
      int f = f0 + u;
      ull key = pbuf[f*256 + tid];
      if (f < cnt && key > kv[19]) {
        ull ck = key;
#pragma unroll
        for (int s = 0; s < 20; ++s) {
          bool sw = ck > kv[s];
          ull tv = kv[s];
          kv[s] = sw ? ck : kv[s];
          ck = sw ? tv : ck;
        }
      }
    }
  };

  auto flush = [&]() {
    insert5(0);
    if (__any(cnt > 5)) insert5(5);
    cnt = 0;
    // row threshold = max of kv[19] over the row's 4 quad-lanes (exact lower bound)
    ull t = kv[19];
    ull t2 = __shfl_xor(t, 16); t = t2 > t ? t2 : t;
    t2 = __shfl_xor(t, 32);     t = t2 > t ? t2 : t;
    if (t != 0ull) {
      u32 hk = (u32)(t >> 32);
      u32 u = (hk >> 31) ? (hk ^ 0x80000000u) : ~hk;
      fthresh = __uint_as_float(u);
    }
  };

  bf16x8 A0[4], A1[4];
  auto col16of = [&](int u) { return (w + (u >> 2)*4)*64 + (u & 3)*16; };
  auto loadTo = [&](bf16x8 (&A)[4], int u) {
    const int col16 = col16of(u);
    const __bf16* ph = Cbh + (size_t)(col16 + L15)*64 + quad*8;
    const __bf16* pl = Cbl + (size_t)(col16 + L15)*64 + quad*8;
    A[0] = *reinterpret_cast<const bf16x8*>(ph);
    A[1] = *reinterpret_cast<const bf16x8*>(ph + 32);
    A[2] = *reinterpret_cast<const bf16x8*>(pl);
    A[3] = *reinterpret_cast<const bf16x8*>(pl + 32);
  };
  auto body = [&](bf16x8 (&A)[4], int u) {
    const int col16 = col16of(u);
    f32x4 acc = (f32x4){0.f, 0.f, 0.f, 0.f};
    acc = __builtin_amdgcn_mfma_f32_16x16x32_bf16(A[0], rh0, acc, 0, 0, 0);
    acc = __builtin_amdgcn_mfma_f32_16x16x32_bf16(A[1], rh1, acc, 0, 0, 0);
    acc = __builtin_amdgcn_mfma_f32_16x16x32_bf16(A[0], rl0, acc, 0, 0, 0);
    acc = __builtin_amdgcn_mfma_f32_16x16x32_bf16(A[1], rl1, acc, 0, 0, 0);
    acc = __builtin_amdgcn_mfma_f32_16x16x32_bf16(A[2], rh0, acc, 0, 0, 0);
    acc = __builtin_amdgcn_mfma_f32_16x16x32_bf16(A[3], rh1, acc, 0, 0, 0);
    float4 xv = *reinterpret_cast<const float4*>(&sxx[col16 + quad*4]);
    const float xvr[4] = {xv.x, xv.y, xv.z, xv.w};
#pragma unroll
    for (int r = 0; r < 4; ++r) {
      float e = 2.0f*acc[r] - xvr[r];
      if (e >= fthresh) {
        int j = col16 + quad*4 + r;
        u32 uu = __float_as_uint(e);
        u32 hk = uu ^ ((u32)((int)uu >> 31) | 0x80000000u);
        pbuf[cnt*256 + tid] = (((ull)hk) << 32) | (u32)~(u32)j;
        ++cnt;
      }
    }
    if (__any(cnt >= 6)) flush();   // cap 10: max cnt 5+4=9
  };

  loadTo(A0, 0);
  for (int u = 0; u < 64; u += 2) {
    loadTo(A1, u + 1);
    body(A0, u);
    if (u + 2 < 64) loadTo(A0, u + 2);
    body(A1, u + 1);
  }
  flush();

  __syncthreads();   // sxx/pbuf dead -> dump layout: dump[(w*64+L)*20 + k]
#pragma unroll
  for (int k = 0; k < Kn; ++k) smem[((size_t)w*64 + L)*20 + k] = kv[k];
  __syncthreads();

  // stage 1: 64 threads, (wave wv, row r): merge the 4 quad lists -> regs lv[20]
  ull lv[20];
  const int wv = tid >> 4, r16 = tid & 15;
  if (tid < 64) {
    ull h[4]; int pc[4];
#pragma unroll
    for (int q = 0; q < 4; ++q) { h[q] = smem[((size_t)wv*64 + q*16 + r16)*20]; pc[q] = 0; }
#pragma unroll
    for (int k = 0; k < Kn; ++k) {
      ull best = h[0]; int sel = 0;
      if (h[1] > best) { best = h[1]; sel = 1; }
      if (h[2] > best) { best = h[2]; sel = 2; }
      if (h[3] > best) { best = h[3]; sel = 3; }
      lv[k] = best;
      int np_ = ++pc[sel];
      h[sel] = (np_ < 20) ? smem[((size_t)wv*64 + sel*16 + r16)*20 + np_] : 0ull;
    }
  }
  __syncthreads();
  if (tid < 64) {
#pragma unroll
    for (int k = 0; k < Kn; ++k) smem[((size_t)wv*16 + r16)*20 + k] = lv[k];
  }
  __syncthreads();

  // stage 2: 16 threads, row r: merge the 4 wave lists -> idx2
  if (tid < 16) {
    const int r = tid;
    ull h[4]; int pc[4];
#pragma unroll
    for (int q = 0; q < 4; ++q) { h[q] = smem[((size_t)q*16 + r)*20]; pc[q] = 0; }
    size_t obase = ((size_t)b*Np + n0 + r)*Kn;
#pragma unroll
    for (int k = 0; k < Kn; ++k) {
      ull best = h[0]; int sel = 0;
      if (h[1] > best) { best = h[1]; sel = 1; }
      if (h[2] > best) { best = h[2]; sel = 2; }
      if (h[3] > best) { best = h[3]; sel = 3; }
      idx2[obase + k] = (int)~(u32)best;
      int np_ = ++pc[sel];
      h[sel] = (np_ < 20) ? smem[((size_t)sel*16 + r)*20 + np_] : 0ull;
    }
  }
}

// ---------------- K3: edgeconv2 (one wave per point, W2 rows in registers) ----------------
__global__ __launch_bounds__(256) void k3_edge2(
    const __bf16* __restrict__ xh, const __bf16* __restrict__ xl,
    const int* __restrict__ idx2,
    const float* __restrict__ W2,
    const float* __restrict__ g2, const float* __restrict__ b2,
    const float* __restrict__ m2, const float* __restrict__ v2,
    float* __restrict__ x2)
{
  __shared__ float scen[4][64];
  __shared__ float snbr[4][64];
  const int b = blockIdx.y;
  const int tid = threadIdx.x;
  const int w = tid >> 6, L = tid & 63;
  const int n = blockIdx.x*4 + w;

  float4 w2a[16], w2b[16];
#pragma unroll
  for (int q = 0; q < 16; ++q) {
    w2a[q] = reinterpret_cast<const float4*>(W2 + L*128)[q];
    w2b[q] = reinterpret_cast<const float4*>(W2 + L*128 + 64)[q];
  }
  const float sc2 = g2[L]/sqrtf(v2[L]+EPSf);
  const float m2o = m2[L], b2o = b2[L];

  float cen = (float)xh[((size_t)b*Np + n)*64 + L] + (float)xl[((size_t)b*Np + n)*64 + L];
  scen[w][L] = cen;
  __syncthreads();
  float u = 0.f, t2 = 0.f;
#pragma unroll
  for (int q = 0; q < 16; ++q) {
    float4 cv = *reinterpret_cast<const float4*>(&scen[w][q*4]);
    u  += w2a[q].x*cv.x + w2a[q].y*cv.y + w2a[q].z*cv.z + w2a[q].w*cv.w;
    t2 += w2b[q].x*cv.x + w2b[q].y*cv.y + w2b[q].z*cv.z + w2b[q].w*cv.w;
  }

  const int* ip = idx2 + ((size_t)b*Np + n)*Kn;
  float xm = NEGINF;
  int j0 = ip[0];
  float cur = (float)xh[((size_t)b*Np + j0)*64 + L] + (float)xl[((size_t)b*Np + j0)*64 + L];
  for (int k = 0; k < Kn; ++k) {
    float nxt = 0.f;
    if (k+1 < Kn) {
      int jn = ip[k+1];
      nxt = (float)xh[((size_t)b*Np + jn)*64 + L] + (float)xl[((size_t)b*Np + jn)*64 + L];
    }
    snbr[w][L] = cur;
    float a = 0.f;
#pragma unroll
    for (int q = 0; q < 16; ++q) {
      float4 nv = *reinterpret_cast<const float4*>(&snbr[w][q*4]);
      a += w2a[q].x*nv.x + w2a[q].y*nv.y + w2a[q].z*nv.z + w2a[q].w*nv.w;
    }
    float vv = a - u + t2;
    float hh = (vv - m2o)*sc2 + b2o;
    hh = hh >= 0.f ? hh : SLOPE*hh;
    xm = fmaxf(xm, hh);
    cur = nxt;
  }
  x2[(b*64 + L)*Np + n] = xm;
}

// ---------------- K4: conv5 + per-block max over n ----------------
__global__ __launch_bounds__(256) void k4_conv5max(
    const float* __restrict__ x1, const float* __restrict__ x2,
    const float* __restrict__ W5,
    const float* __restrict__ g5, const float* __restrict__ b5,
    const float* __restrict__ m5, const float* __restrict__ v5,
    float* __restrict__ partials)  // (B,128,64)
{
  const int b = blockIdx.y, nb = blockIdx.x;
  const int tid = threadIdx.x;
  const int p = tid & 63;
  const int g = __builtin_amdgcn_readfirstlane(tid >> 6);
  const int n = nb*64 + p;
  float xcr[128];
#pragma unroll
  for (int c = 0; c < 64; ++c) {
    xcr[c]    = x1[(b*64 + c)*Np + n];
    xcr[64+c] = x2[(b*64 + c)*Np + n];
  }
  for (int oi = 0; oi < 32; ++oi) {
    const int o = g*32 + oi;
    const float* wr = W5 + o*128;
    float dot = 0.f;
#pragma unroll
    for (int c = 0; c < 128; c += 4) {
      float4 wv = *reinterpret_cast<const float4*>(wr + c);
      dot += wv.x*xcr[c] + wv.y*xcr[c+1] + wv.z*xcr[c+2] + wv.w*xcr[c+3];
    }
    float hv = (dot - m5[o])*(g5[o]/sqrtf(v5[o]+EPSf)) + b5[o];
    hv = hv >= 0.f ? hv : SLOPE*hv;
#pragma unroll
    for (int off = 1; off < 64; off <<= 1) hv = fmaxf(hv, __shfl_xor(hv, off));
    if (p == 0) partials[(b*128 + o)*64 + nb] = hv;
  }
}

// ---------------- K5: reduce partial maxima -> gmax, then t6 = W6a * gmax ----------------
__global__ __launch_bounds__(256) void k5_reduce_t6(
    const float* __restrict__ partials, const float* __restrict__ W6,
    float* __restrict__ t6)  // (B,256)
{
  __shared__ float sg[128];
  const int b = blockIdx.x;
  const int tid = threadIdx.x;
  if (tid < 128) {
    float m = NEGINF;
    for (int w = 0; w < 64; ++w) m = fmaxf(m, partials[(b*128 + tid)*64 + w]);
    sg[tid] = m;
  }
  __syncthreads();
  float a = 0.f;
#pragma unroll
  for (int c = 0; c < 128; c += 4) {
    float4 wv = *reinterpret_cast<const float4*>(W6 + tid*256 + c);
    a += wv.x*sg[c] + wv.y*sg[c+1] + wv.z*sg[c+2] + wv.w*sg[c+3];
  }
  t6[b*256 + tid] = a;
}

// ---------------- K6: conv6 (W6b part + t6) + bn + lrelu + W9 dot ----------------
__global__ __launch_bounds__(256) void k6_conv6_out(
    const float* __restrict__ x1, const float* __restrict__ x2,
    const float* __restrict__ W6, const float* __restrict__ t6,
    const float* __restrict__ g6, const float* __restrict__ b6,
    const float* __restrict__ m6, const float* __restrict__ v6,
    const float* __restrict__ W9,
    float* __restrict__ out)
{
  __shared__ float red[4][64];
  const int b = blockIdx.y, nb = blockIdx.x;
  const int tid = threadIdx.x;
  const int p = tid & 63;
  const int g = __builtin_amdgcn_readfirstlane(tid >> 6);
  const int n = nb*64 + p;
  float xcr[128];
#pragma unroll
  for (int c = 0; c < 64; ++c) {
    xcr[c]    = x1[(b*64 + c)*Np + n];
    xcr[64+c] = x2[(b*64 + c)*Np + n];
  }
  float oacc = 0.f;
  for (int oi = 0; oi < 64; ++oi) {
    const int o = g*64 + oi;
    const float* wr = W6 + o*256 + 128;
    float dot = t6[b*256 + o];
#pragma unroll
    for (int c = 0; c < 128; c += 4) {
      float4 wv = *reinterpret_cast<const float4*>(wr + c);
      dot += wv.x*xcr[c] + wv.y*xcr[c+1] + wv.z*xcr[c+2] + wv.w*xcr[c+3];
    }
    float hv = (dot - m6[o])*(g6[o]/sqrtf(v6[o]+EPSf)) + b6[o];
    hv = hv >= 0.f ? hv : SLOPE*hv;
    oacc += W9[o]*hv;
  }
  red[g][p] = oacc;
  __syncthreads();
  if (tid < 64)
    out[b*Np + nb*64 + tid] = red[0][tid] + red[1][tid] + red[2][tid] + red[3][tid];
}

extern "C" void kernel_launch(void* const* d_in, const int* in_sizes, int n_in,
                              void* d_out, int out_size, void* d_ws, size_t ws_size,
                              hipStream_t stream) {
  const float* x  = (const float*)d_in[0];
  const float* W1 = (const float*)d_in[1];
  const float* g1 = (const float*)d_in[2];
  const float* b1 = (const float*)d_in[3];
  const float* m1 = (const float*)d_in[4];
  const float* v1 = (const float*)d_in[5];
  const float* W2 = (const float*)d_in[6];
  const float* g2 = (const float*)d_in[7];
  const float* b2 = (const float*)d_in[8];
  const float* m2 = (const float*)d_in[9];
  const float* v2 = (const float*)d_in[10];
  const float* W5 = (const float*)d_in[11];
  const float* g5 = (const float*)d_in[12];
  const float* b5 = (const float*)d_in[13];
  const float* m5 = (const float*)d_in[14];
  const float* v5 = (const float*)d_in[15];
  const float* W6 = (const float*)d_in[16];
  const float* g6 = (const float*)d_in[17];
  const float* b6 = (const float*)d_in[18];
  const float* m6 = (const float*)d_in[19];
  const float* v6 = (const float*)d_in[20];
  const float* W9 = (const float*)d_in[21];
  float* out = (float*)d_out;

  float* F = (float*)d_ws;
  float*  x1    = F;                         // 1048576
  float*  xx2   = F + 1048576;               // 16384
  __bf16* x1h   = (__bf16*)(F + 1064960);    // 524288 float-slots
  __bf16* x1l   = (__bf16*)(F + 1589248);    // 524288
  float*  x2    = F + 2113536;               // 1048576
  int*    idx2  = (int*)(F + 3162112);       // 327680
  float*  t6    = F + 3489792;               // 1024
  float*  parts = F + 3490816;               // 32768

  k1_knn1_edge1<<<dim3(64,4), 256, 0, stream>>>(x, W1, g1, b1, m1, v1, x1, x1h, x1l, xx2);
  k2_knn2<<<dim3(256,4), 256, 0, stream>>>(x1h, x1l, xx2, idx2);
  k3_edge2<<<dim3(1024,4), 256, 0, stream>>>(x1h, x1l, idx2, W2, g2, b2, m2, v2, x2);
  k4_conv5max<<<dim3(64,4), 256, 0, stream>>>(x1, x2, W5, g5, b5, m5, v5, parts);
  k5_reduce_t6<<<4, 256, 0, stream>>>(parts, W6, t6);
  k6_conv6_out<<<dim3(64,4), 256, 0, stream>>>(x1, x2, W6, t6, g6, b6, m6, v6, W9, out);
}

// Round 11
// 798.661 us; speedup vs baseline: 2.3619x; 2.3619x over previous
//
#include <hip/hip_runtime.h>
#include <math.h>

#define NEGINF (-INFINITY)
constexpr int Np = 4096;
constexpr int Kn = 20;
constexpr float EPSf = 1e-5f;
constexpr float SLOPE = 0.2f;

typedef __bf16 bf16x8 __attribute__((ext_vector_type(8)));
typedef float f32x4 __attribute__((ext_vector_type(4)));
typedef unsigned long long ull;
typedef unsigned int u32;

// ---------------- K1: knn1 + edgeconv1 fused (u64 exact keys, round-9 proven) ----------------
__global__ __launch_bounds__(256) void k1_knn1_edge1(
    const float* __restrict__ x, const float* __restrict__ W1,
    const float* __restrict__ g1, const float* __restrict__ b1,
    const float* __restrict__ m1, const float* __restrict__ v1,
    float* __restrict__ x1, __bf16* __restrict__ x1h, __bf16* __restrict__ x1l,
    float* __restrict__ xx2)
{
  __shared__ ull smem[6144];   // ph1: pbuf[24][256]; ph2: dump[4][64][20] + midx

  const int b = blockIdx.y;
  const int n0 = blockIdx.x * 64;
  const int tid = threadIdx.x;
  const int w = tid >> 6, L = tid & 63;
  const float* __restrict__ xr = x + (size_t)b*2*Np;
  const float* __restrict__ yr = xr + Np;

  const int n = n0 + L;
  const float px = xr[n], py = yr[n];

  ull kv[20];
#pragma unroll
  for (int s = 0; s < 20; ++s) kv[s] = 0ull;
  u32 u_cut = 0xFFFFFFFFu;
  int cnt = 0;

  auto flushK = [&]() {
#pragma unroll 1
    for (int f0 = 0; f0 < 24; f0 += 8) {
      if (__all(f0 >= cnt)) break;
      ull t0[8];
#pragma unroll
      for (int u = 0; u < 8; ++u) t0[u] = smem[(f0+u)*256 + tid];
#pragma unroll
      for (int u = 0; u < 8; ++u) {        // static t0 index only
        int f = f0 + u;
        ull key = t0[u];
        if (f < cnt && key > kv[19]) {
          ull ck = key;
#pragma unroll
          for (int s = 0; s < 20; ++s) {
            bool sw = ck > kv[s];
            ull tv = kv[s];
            kv[s] = sw ? ck : kv[s];
            ck = sw ? tv : ck;
          }
        }
      }
    }
    cnt = 0;
    u_cut = ~(u32)(kv[19] >> 32);
  };

  const int base = w * 1024;
  for (int j0 = base; j0 < base + 1024; j0 += 16) {
#pragma unroll
    for (int c = 0; c < 4; ++c) {
      float4 xv = *reinterpret_cast<const float4*>(xr + j0 + c*4);  // uniform -> s_load
      float4 yv = *reinterpret_cast<const float4*>(yr + j0 + c*4);
      const float xs[4] = {xv.x, xv.y, xv.z, xv.w};
      const float ys[4] = {yv.x, yv.y, yv.z, yv.w};
#pragma unroll
      for (int r = 0; r < 4; ++r) {
        float dx = xs[r] - px, dy = ys[r] - py;
        float s = dx*dx + dy*dy;
        u32 ub = __float_as_uint(s);
        if (ub <= u_cut) {
          int j = j0 + c*4 + r;
          smem[cnt*256 + tid] = (((ull)~ub) << 32) | (u32)~(u32)j;
          ++cnt;
        }
      }
    }
    if (__any(cnt >= 8)) flushK();
  }
  flushK();

  __syncthreads();             // pbuf dead; switch to dump layout
#pragma unroll
  for (int k = 0; k < Kn; ++k) smem[((size_t)w*64 + L)*20 + k] = kv[k];
  __syncthreads();

  u32* midx = (u32*)(smem + 5120);   // 64 x 20 merged indices (disjoint region)
  if (tid < 64) {
    const int p = tid;
    ull h[4]; int pc[4];
#pragma unroll
    for (int q = 0; q < 4; ++q) { h[q] = smem[((size_t)q*64 + p)*20]; pc[q] = 0; }
#pragma unroll
    for (int k = 0; k < Kn; ++k) {
      ull best = h[0]; int sel = 0;
      if (h[1] > best) { best = h[1]; sel = 1; }
      if (h[2] > best) { best = h[2]; sel = 2; }
      if (h[3] > best) { best = h[3]; sel = 3; }
      midx[p*20 + k] = (u32)~(u32)best;
      int np_ = ++pc[sel];
      h[sel] = (np_ < 20) ? smem[((size_t)sel*64 + p)*20 + np_] : 0ull;
    }
  }
  __syncthreads();

  // phase 3: edgeconv1 — wave w handles points w*16..w*16+15, lane = channel o
  const int o = L;
  const float4 w1v = reinterpret_cast<const float4*>(W1)[o];
  const float sc = g1[o] / sqrtf(v1[o] + EPSf);
  const float mo = m1[o], bo = b1[o];

  for (int pi = 0; pi < 16; ++pi) {
    const int p = w*16 + pi;
    const int np = n0 + p;
    const float cx0 = xr[np], cx1 = yr[np];          // uniform
    const float cterm = (w1v.z - w1v.x)*cx0 + (w1v.w - w1v.y)*cx1;
    float xm = NEGINF;
#pragma unroll
    for (int k = 0; k < Kn; ++k) {
      int j = __builtin_amdgcn_readfirstlane(midx[p*20 + k]);
      float xj = xr[j], yj = yr[j];                  // s_loads
      float vv = w1v.x*xj + w1v.y*yj + cterm;
      float h = (vv - mo)*sc + bo;
      h = h >= 0.f ? h : SLOPE*h;
      xm = fmaxf(xm, h);
    }
    x1[(b*64 + o)*Np + np] = xm;
    __bf16 hb = (__bf16)xm;
    __bf16 lb = (__bf16)(xm - (float)hb);
    size_t tbase = ((size_t)b*Np + np)*64 + o;
    x1h[tbase] = hb;
    x1l[tbase] = lb;
    float s = xm*xm;
#pragma unroll
    for (int off = 1; off < 64; off <<= 1) s += __shfl_xor(s, off);
    if (L == 0) xx2[b*Np + np] = s;
  }
}

// ---------------- K2: knn2 — two-phase exact top-20 ----------------
// grid (256 rowblocks, B), 256 thr. Block: 16 rows x 4096 cols; wave w takes tiles tt==w mod 4.
// MFMA D[n=L15 -> row][m=quad*4+r -> col]; lane owns one row (n0+L15).
// Phase A: exact per-row 20th VALUE (u32 sortable, no index bits -> kv is 20 VGPRs).
// Phase B: recompute gram (bitwise identical), collect j: e>v20 -> definite, e==v20 -> ties,
//          finalize ties ascending j (matches top_k tie-break). idx2 order is irrelevant
//          downstream (max-pool).
__global__ __launch_bounds__(256) void k2_knn2(
    const __bf16* __restrict__ xh, const __bf16* __restrict__ xl,
    const float* __restrict__ xx2, int* __restrict__ idx2)
{
  __shared__ u32 smem[10544];          // 42.2 KB
  float* sxx   = (float*)smem;         // [0,4096)      col norms, live all kernel
  u32* pbuf    = smem + 4096;          // [4096,6656)   phase A push stacks [10][256]
  u32* dumpA   = smem + 4096;          // [4096,9216)   lane lists [4][64][20] (after pbuf dead)
  u32* merged1 = smem + 9216;          // [9216,10496)  stage-1 lists [4][16][20]
  u32* v20u    = smem + 10496;         // [10496,10512) per-row 20th value
  u32* cntGT   = smem + 10512;         // [10512,10528)
  u32* cntEQ   = smem + 10528;         // [10528,10544)
  u32* jbuf    = smem + 4096;          // [4096,4416)   phase B: definite js [16][20]
  u32* tiebuf  = smem + 4416;          // [4416,4928)   phase B: tie js [16][32]

  const int b = blockIdx.y;
  const int n0 = blockIdx.x * 16;
  const int tid = threadIdx.x;
  const int w = tid >> 6, L = tid & 63;
  const int L15 = L & 15, quad = L >> 4;

  for (int j = tid*4; j < Np; j += 1024)
    *reinterpret_cast<float4*>(&sxx[j]) = *reinterpret_cast<const float4*>(&xx2[(size_t)b*Np + j]);

  // B operand: rows n0..n0+15 (resident all kernel)
  const __bf16* Rh = xh + ((size_t)b*Np + n0)*64;
  const __bf16* Rl = xl + ((size_t)b*Np + n0)*64;
  bf16x8 rh0 = *reinterpret_cast<const bf16x8*>(Rh + L15*64 +  0 + quad*8);
  bf16x8 rh1 = *reinterpret_cast<const bf16x8*>(Rh + L15*64 + 32 + quad*8);
  bf16x8 rl0 = *reinterpret_cast<const bf16x8*>(Rl + L15*64 +  0 + quad*8);
  bf16x8 rl1 = *reinterpret_cast<const bf16x8*>(Rl + L15*64 + 32 + quad*8);

  const __bf16* Cbh = xh + (size_t)b*Np*64;
  const __bf16* Cbl = xl + (size_t)b*Np*64;

  u32 kv[20];
#pragma unroll
  for (int s = 0; s < 20; ++s) kv[s] = 0u;
  float fthresh = NEGINF;
  int cnt = 0;

  __syncthreads();   // sxx ready

  auto flush = [&]() {
#pragma unroll 1
    for (int f = 0; f < 10; ++f) {     // dynamic LDS addressing is fine (no reg array)
      if (__all(f >= cnt)) break;
      u32 key = pbuf[f*256 + tid];
      if (f < cnt && key > kv[19]) {
        u32 ck = key;
#pragma unroll
        for (int s = 0; s < 20; ++s) {
          bool sw = ck > kv[s];
          u32 tv = kv[s];
          kv[s] = sw ? ck : kv[s];
          ck = sw ? tv : ck;
        }
      }
    }
    cnt = 0;
    u32 t = kv[19];
    u32 t2 = __shfl_xor(t, 16); t = t2 > t ? t2 : t;
    t2 = __shfl_xor(t, 32);     t = t2 > t ? t2 : t;
    if (t != 0u) {
      u32 uu = (t >> 31) ? (t ^ 0x80000000u) : ~t;   // exact unsort
      fthresh = __uint_as_float(uu);
    }
  };

  // ---- Phase A: exact per-lane top-20 values ----
  for (int t = 0; t < 16; ++t) {
    const int colbase = (w + t*4) * 64;
#pragma unroll
    for (int s = 0; s < 4; ++s) {
      const int col16 = colbase + s*16;
      const __bf16* ph = Cbh + (size_t)(col16 + L15)*64 + quad*8;
      const __bf16* pl = Cbl + (size_t)(col16 + L15)*64 + quad*8;
      bf16x8 a0 = *reinterpret_cast<const bf16x8*>(ph);
      bf16x8 a1 = *reinterpret_cast<const bf16x8*>(ph + 32);
      bf16x8 a2 = *reinterpret_cast<const bf16x8*>(pl);
      bf16x8 a3 = *reinterpret_cast<const bf16x8*>(pl + 32);
      f32x4 acc = (f32x4){0.f, 0.f, 0.f, 0.f};
      acc = __builtin_amdgcn_mfma_f32_16x16x32_bf16(a0, rh0, acc, 0, 0, 0);
      acc = __builtin_amdgcn_mfma_f32_16x16x32_bf16(a1, rh1, acc, 0, 0, 0);
      acc = __builtin_amdgcn_mfma_f32_16x16x32_bf16(a0, rl0, acc, 0, 0, 0);
      acc = __builtin_amdgcn_mfma_f32_16x16x32_bf16(a1, rl1, acc, 0, 0, 0);
      acc = __builtin_amdgcn_mfma_f32_16x16x32_bf16(a2, rh0, acc, 0, 0, 0);
      acc = __builtin_amdgcn_mfma_f32_16x16x32_bf16(a3, rh1, acc, 0, 0, 0);
      float4 xv = *reinterpret_cast<const float4*>(&sxx[col16 + quad*4]);
      const float xvr[4] = {xv.x, xv.y, xv.z, xv.w};
#pragma unroll
      for (int r = 0; r < 4; ++r) {
        float e = 2.0f*acc[r] - xvr[r];
        if (e >= fthresh) {
          u32 uu = __float_as_uint(e);
          u32 hk = uu ^ ((u32)((int)uu >> 31) | 0x80000000u);
          pbuf[cnt*256 + tid] = hk;
          ++cnt;
        }
      }
      if (__any(cnt >= 6)) flush();   // cap 10: max cnt 5+4=9
    }
  }
  flush();

  __syncthreads();   // pbuf dead -> dumpA
#pragma unroll
  for (int k = 0; k < Kn; ++k) dumpA[((size_t)w*64 + L)*20 + k] = kv[k];
  __syncthreads();

  // stage 1: 64 threads, (wave wv, row r16): 4-way value merge -> merged1
  if (tid < 64) {
    const int wv = tid >> 4, r16 = tid & 15;
    u32 h[4]; int pc[4];
#pragma unroll
    for (int q = 0; q < 4; ++q) { h[q] = dumpA[((size_t)wv*64 + q*16 + r16)*20]; pc[q] = 0; }
#pragma unroll
    for (int k = 0; k < Kn; ++k) {
      u32 best = h[0]; int sel = 0;
      if (h[1] > best) { best = h[1]; sel = 1; }
      if (h[2] > best) { best = h[2]; sel = 2; }
      if (h[3] > best) { best = h[3]; sel = 3; }
      merged1[((size_t)wv*16 + r16)*20 + k] = best;
      int np_ = ++pc[sel];
      h[sel] = (np_ < 20) ? dumpA[((size_t)wv*64 + sel*16 + r16)*20 + np_] : 0u;
    }
  }
  __syncthreads();

  // stage 2: 16 threads, row r: 4-way merge, keep only the 20th value; zero counters
  if (tid < 16) {
    const int r = tid;
    u32 h[4]; int pc[4];
#pragma unroll
    for (int q = 0; q < 4; ++q) { h[q] = merged1[((size_t)q*16 + r)*20]; pc[q] = 0; }
    u32 last = 0u;
#pragma unroll
    for (int k = 0; k < Kn; ++k) {
      u32 best = h[0]; int sel = 0;
      if (h[1] > best) { best = h[1]; sel = 1; }
      if (h[2] > best) { best = h[2]; sel = 2; }
      if (h[3] > best) { best = h[3]; sel = 3; }
      last = best;
      int np_ = ++pc[sel];
      h[sel] = (np_ < 20) ? merged1[((size_t)sel*16 + r)*20 + np_] : 0u;
    }
    v20u[r] = last;
    cntGT[r] = 0;
    cntEQ[r] = 0;
  }
  __syncthreads();

  // ---- Phase B: recompute (bitwise identical), collect indices ----
  for (int t = 0; t < 16; ++t) {
    const int colbase = (w + t*4) * 64;
#pragma unroll
    for (int s = 0; s < 4; ++s) {
      const int col16 = colbase + s*16;
      const __bf16* ph = Cbh + (size_t)(col16 + L15)*64 + quad*8;
      const __bf16* pl = Cbl + (size_t)(col16 + L15)*64 + quad*8;
      bf16x8 a0 = *reinterpret_cast<const bf16x8*>(ph);
      bf16x8 a1 = *reinterpret_cast<const bf16x8*>(ph + 32);
      bf16x8 a2 = *reinterpret_cast<const bf16x8*>(pl);
      bf16x8 a3 = *reinterpret_cast<const bf16x8*>(pl + 32);
      f32x4 acc = (f32x4){0.f, 0.f, 0.f, 0.f};
      acc = __builtin_amdgcn_mfma_f32_16x16x32_bf16(a0, rh0, acc, 0, 0, 0);
      acc = __builtin_amdgcn_mfma_f32_16x16x32_bf16(a1, rh1, acc, 0, 0, 0);
      acc = __builtin_amdgcn_mfma_f32_16x16x32_bf16(a0, rl0, acc, 0, 0, 0);
      acc = __builtin_amdgcn_mfma_f32_16x16x32_bf16(a1, rl1, acc, 0, 0, 0);
      acc = __builtin_amdgcn_mfma_f32_16x16x32_bf16(a2, rh0, acc, 0, 0, 0);
      acc = __builtin_amdgcn_mfma_f32_16x16x32_bf16(a3, rh1, acc, 0, 0, 0);
      float4 xv = *reinterpret_cast<const float4*>(&sxx[col16 + quad*4]);
      const float xvr[4] = {xv.x, xv.y, xv.z, xv.w};
      const u32 vt = v20u[L15];
#pragma unroll
      for (int r = 0; r < 4; ++r) {
        float e = 2.0f*acc[r] - xvr[r];
        u32 uu = __float_as_uint(e);
        u32 se = uu ^ ((u32)((int)uu >> 31) | 0x80000000u);
        if (se >= vt) {
          int j = col16 + quad*4 + r;
          if (se > vt) {
            u32 pos = atomicAdd(&cntGT[L15], 1u);
            if (pos < 20u) jbuf[L15*20 + pos] = (u32)j;
          } else {
            u32 pos = atomicAdd(&cntEQ[L15], 1u);
            if (pos < 32u) tiebuf[L15*32 + pos] = (u32)j;
          }
        }
      }
    }
  }
  __syncthreads();

  // finalize: 16 threads/row — definite js + lowest-j ties to fill 20
  if (tid < 16) {
    const int r = tid;
    int ngt = (int)cntGT[r]; ngt = ngt > 20 ? 20 : ngt;   // math guarantees <=19
    int neq = (int)cntEQ[r]; neq = neq > 32 ? 32 : neq;
    size_t obase = ((size_t)b*Np + n0 + r)*Kn;
#pragma unroll 1
    for (int k = 0; k < ngt; ++k) idx2[obase + k] = (int)jbuf[r*20 + k];
    int need = Kn - ngt;
#pragma unroll 1
    for (int k = 0; k < need; ++k) {
      u32 best = 0xFFFFFFFFu; int bi = -1;
#pragma unroll 1
      for (int i = 0; i < neq; ++i) {
        u32 v = tiebuf[r*32 + i];
        if (v < best) { best = v; bi = i; }
      }
      if (bi >= 0) tiebuf[r*32 + bi] = 0xFFFFFFFFu;
      idx2[obase + ngt + k] = (bi >= 0) ? (int)best : 0;
    }
  }
}

// ---------------- K3a: Y = W2a * x1 (column-major out), W2a staged in LDS ----------------
__global__ __launch_bounds__(256) void k3a_Y(
    const __bf16* __restrict__ xh, const __bf16* __restrict__ xl,
    const float* __restrict__ W2, float* __restrict__ Ycol)
{
  __shared__ float w2s[64][65];
  __shared__ float xs[4][16][65];
  const int b = blockIdx.y;
  const int tid = threadIdx.x;
  const int w = tid >> 6, L = tid & 63;

  for (int i = tid; i < 4096; i += 256) {
    int o = i >> 6, c = i & 63;
    w2s[o][c] = W2[o*128 + c];
  }
  __syncthreads();

  const int p0 = blockIdx.x*64 + w*16;
  for (int i = 0; i < 16; ++i) {
    size_t base = ((size_t)b*Np + p0 + i)*64 + L;
    xs[w][i][L] = (float)xh[base] + (float)xl[base];
  }
  for (int i = 0; i < 16; ++i) {
    float y = 0.f;
#pragma unroll
    for (int c = 0; c < 64; ++c)
      y += w2s[L][c] * xs[w][i][c];
    Ycol[((size_t)b*Np + p0 + i)*64 + L] = y;
  }
}

// ---------------- K3b: edgeconv2 gather — x2[o][n] = max_k lrelu(bn(Y[:,jk] + Z[:,n])) ---
__global__ __launch_bounds__(256) void k3b_edge2(
    const __bf16* __restrict__ xh, const __bf16* __restrict__ xl,
    const float* __restrict__ W2, const int* __restrict__ idx2,
    const float* __restrict__ Ycol,
    const float* __restrict__ g2, const float* __restrict__ b2,
    const float* __restrict__ m2, const float* __restrict__ v2,
    float* __restrict__ x2)
{
  __shared__ float w2d[64][65];
  __shared__ float xs[4][16][65];
  const int b = blockIdx.y;
  const int tid = threadIdx.x;
  const int w = tid >> 6, L = tid & 63;

  for (int i = tid; i < 4096; i += 256) {
    int o = i >> 6, c = i & 63;
    w2d[o][c] = W2[o*128 + 64 + c] - W2[o*128 + c];
  }
  __syncthreads();

  const float sc2 = g2[L]/sqrtf(v2[L]+EPSf);
  const float m2o = m2[L], b2o = b2[L];

  const int p0 = blockIdx.x*64 + w*16;
  for (int i = 0; i < 16; ++i) {
    size_t base = ((size_t)b*Np + p0 + i)*64 + L;
    xs[w][i][L] = (float)xh[base] + (float)xl[base];
  }
  for (int i = 0; i < 16; ++i) {
    const int n = p0 + i;
    float z = 0.f;
#pragma unroll
    for (int c = 0; c < 64; ++c)
      z += w2d[L][c] * xs[w][i][c];
    const int* ip = idx2 + ((size_t)b*Np + n)*Kn;   // uniform -> s_loads
    float xm = NEGINF;
#pragma unroll
    for (int k = 0; k < Kn; ++k) {
      int j = ip[k];
      float yv = Ycol[((size_t)b*Np + j)*64 + L];   // coalesced 256B column
      float vv = yv + z;
      float hh = (vv - m2o)*sc2 + b2o;
      hh = hh >= 0.f ? hh : SLOPE*hh;
      xm = fmaxf(xm, hh);
    }
    x2[(b*64 + L)*Np + n] = xm;
  }
}

// ---------------- K4: conv5 + per-block max, two 64-channel passes ----------------
__global__ __launch_bounds__(256) void k4_conv5max(
    const float* __restrict__ x1, const float* __restrict__ x2,
    const float* __restrict__ W5,
    const float* __restrict__ g5, const float* __restrict__ b5,
    const float* __restrict__ m5, const float* __restrict__ v5,
    float* __restrict__ partials)  // (B,128,64)
{
  const int b = blockIdx.y, nb = blockIdx.x;
  const int tid = threadIdx.x;
  const int p = tid & 63;
  const int g = __builtin_amdgcn_readfirstlane(tid >> 6);
  const int n = nb*64 + p;

  float xcr[64], dotp[32];
#pragma unroll
  for (int c = 0; c < 64; ++c) xcr[c] = x1[(b*64 + c)*Np + n];
#pragma unroll
  for (int oi = 0; oi < 32; ++oi) {
    const float* wr = W5 + (g*32 + oi)*128;
    float d = 0.f;
#pragma unroll
    for (int c = 0; c < 64; c += 4) {
      float4 wv = *reinterpret_cast<const float4*>(wr + c);
      d += wv.x*xcr[c] + wv.y*xcr[c+1] + wv.z*xcr[c+2] + wv.w*xcr[c+3];
    }
    dotp[oi] = d;
  }
#pragma unroll
  for (int c = 0; c < 64; ++c) xcr[c] = x2[(b*64 + c)*Np + n];
#pragma unroll
  for (int oi = 0; oi < 32; ++oi) {
    const int o = g*32 + oi;
    const float* wr = W5 + o*128 + 64;
    float d = dotp[oi];
#pragma unroll
    for (int c = 0; c < 64; c += 4) {
      float4 wv = *reinterpret_cast<const float4*>(wr + c);
      d += wv.x*xcr[c] + wv.y*xcr[c+1] + wv.z*xcr[c+2] + wv.w*xcr[c+3];
    }
    float hv = (d - m5[o])*(g5[o]/sqrtf(v5[o]+EPSf)) + b5[o];
    hv = hv >= 0.f ? hv : SLOPE*hv;
#pragma unroll
    for (int off = 1; off < 64; off <<= 1) hv = fmaxf(hv, __shfl_xor(hv, off));
    if (p == 0) partials[(b*128 + o)*64 + nb] = hv;
  }
}

// ---------------- K5: reduce partial maxima -> gmax, then t6 = W6a * gmax ----------------
__global__ __launch_bounds__(256) void k5_reduce_t6(
    const float* __restrict__ partials, const float* __restrict__ W6,
    float* __restrict__ t6)  // (B,256)
{
  __shared__ float sg[128];
  const int b = blockIdx.x;
  const int tid = threadIdx.x;
  if (tid < 128) {
    float m = NEGINF;
    for (int w = 0; w < 64; ++w) m = fmaxf(m, partials[(b*128 + tid)*64 + w]);
    sg[tid] = m;
  }
  __syncthreads();
  float a = 0.f;
#pragma unroll
  for (int c = 0; c < 128; c += 4) {
    float4 wv = *reinterpret_cast<const float4*>(W6 + tid*256 + c);
    a += wv.x*sg[c] + wv.y*sg[c+1] + wv.z*sg[c+2] + wv.w*sg[c+3];
  }
  t6[b*256 + tid] = a;
}

// ---------------- K6: conv6 + W9, two o-groups x two channel passes ----------------
__global__ __launch_bounds__(256) void k6_conv6_out(
    const float* __restrict__ x1, const float* __restrict__ x2,
    const float* __restrict__ W6, const float* __restrict__ t6,
    const float* __restrict__ g6, const float* __restrict__ b6,
    const float* __restrict__ m6, const float* __restrict__ v6,
    const float* __restrict__ W9,
    float* __restrict__ out)
{
  __shared__ float red[4][64];
  const int b = blockIdx.y, nb = blockIdx.x;
  const int tid = threadIdx.x;
  const int p = tid & 63;
  const int g = __builtin_amdgcn_readfirstlane(tid >> 6);
  const int n = nb*64 + p;

  float oacc = 0.f;
#pragma unroll
  for (int oh = 0; oh < 2; ++oh) {
    float xcr[64], dotp[32];
#pragma unroll
    for (int c = 0; c < 64; ++c) xcr[c] = x1[(b*64 + c)*Np + n];
#pragma unroll
    for (int oi = 0; oi < 32; ++oi) {
      const int o = g*64 + oh*32 + oi;
      const float* wr = W6 + o*256 + 128;
      float d = t6[b*256 + o];
#pragma unroll
      for (int c = 0; c < 64; c += 4) {
        float4 wv = *reinterpret_cast<const float4*>(wr + c);
        d += wv.x*xcr[c] + wv.y*xcr[c+1] + wv.z*xcr[c+2] + wv.w*xcr[c+3];
      }
      dotp[oi] = d;
    }
#pragma unroll
    for (int c = 0; c < 64; ++c) xcr[c] = x2[(b*64 + c)*Np + n];
#pragma unroll
    for (int oi = 0; oi < 32; ++oi) {
      const int o = g*64 + oh*32 + oi;
      const float* wr = W6 + o*256 + 192;
      float d = dotp[oi];
#pragma unroll
      for (int c = 0; c < 64; c += 4) {
        float4 wv = *reinterpret_cast<const float4*>(wr + c);
        d += wv.x*xcr[c] + wv.y*xcr[c+1] + wv.z*xcr[c+2] + wv.w*xcr[c+3];
      }
      float hv = (d - m6[o])*(g6[o]/sqrtf(v6[o]+EPSf)) + b6[o];
      hv = hv >= 0.f ? hv : SLOPE*hv;
      oacc += W9[o]*hv;
    }
  }
  red[g][p] = oacc;
  __syncthreads();
  if (tid < 64)
    out[b*Np + nb*64 + tid] = red[0][tid] + red[1][tid] + red[2][tid] + red[3][tid];
}

extern "C" void kernel_launch(void* const* d_in, const int* in_sizes, int n_in,
                              void* d_out, int out_size, void* d_ws, size_t ws_size,
                              hipStream_t stream) {
  const float* x  = (const float*)d_in[0];
  const float* W1 = (const float*)d_in[1];
  const float* g1 = (const float*)d_in[2];
  const float* b1 = (const float*)d_in[3];
  const float* m1 = (const float*)d_in[4];
  const float* v1 = (const float*)d_in[5];
  const float* W2 = (const float*)d_in[6];
  const float* g2 = (const float*)d_in[7];
  const float* b2 = (const float*)d_in[8];
  const float* m2 = (const float*)d_in[9];
  const float* v2 = (const float*)d_in[10];
  const float* W5 = (const float*)d_in[11];
  const float* g5 = (const float*)d_in[12];
  const float* b5 = (const float*)d_in[13];
  const float* m5 = (const float*)d_in[14];
  const float* v5 = (const float*)d_in[15];
  const float* W6 = (const float*)d_in[16];
  const float* g6 = (const float*)d_in[17];
  const float* b6 = (const float*)d_in[18];
  const float* m6 = (const float*)d_in[19];
  const float* v6 = (const float*)d_in[20];
  const float* W9 = (const float*)d_in[21];
  float* out = (float*)d_out;

  float* F = (float*)d_ws;
  float*  x1    = F;                         // 1048576
  float*  xx2   = F + 1048576;               // 16384
  __bf16* x1h   = (__bf16*)(F + 1064960);    // 524288 float-slots
  __bf16* x1l   = (__bf16*)(F + 1589248);    // 524288
  float*  x2    = F + 2113536;               // 1048576
  float*  Ycol  = F + 3162112;               // 1048576
  int*    idx2  = (int*)(F + 4210688);       // 327680
  float*  t6    = F + 4538368;               // 1024
  float*  parts = F + 4539392;               // 32768

  k1_knn1_edge1<<<dim3(64,4), 256, 0, stream>>>(x, W1, g1, b1, m1, v1, x1, x1h, x1l, xx2);
  k2_knn2<<<dim3(256,4), 256, 0, stream>>>(x1h, x1l, xx2, idx2);
  k3a_Y<<<dim3(64,4), 256, 0, stream>>>(x1h, x1l, W2, Ycol);
  k3b_edge2<<<dim3(64,4), 256, 0, stream>>>(x1h, x1l, W2, idx2, Ycol, g2, b2, m2, v2, x2);
  k4_conv5max<<<dim3(64,4), 256, 0, stream>>>(x1, x2, W5, g5, b5, m5, v5, parts);
  k5_reduce_t6<<<4, 256, 0, stream>>>(parts, W6, t6);
  k6_conv6_out<<<dim3(64,4), 256, 0, stream>>>(x1, x2, W6, t6, g6, b6, m6, v6, W9, out);
}

// Round 12
// 753.058 us; speedup vs baseline: 2.5049x; 1.0606x over previous
//
#include <hip/hip_runtime.h>
#include <math.h>

#define NEGINF (-INFINITY)
constexpr int Np = 4096;
constexpr int Kn = 20;
constexpr float EPSf = 1e-5f;
constexpr float SLOPE = 0.2f;

typedef __bf16 bf16x8 __attribute__((ext_vector_type(8)));
typedef float f32x4 __attribute__((ext_vector_type(4)));
typedef unsigned long long ull;
typedef unsigned int u32;
typedef unsigned short u16;

// ---------------- K1: knn1 + edgeconv1 fused (u64 exact keys, 35KB LDS) ----------------
// grid (64, B), 256 thr. pbuf[16][256] ull (32KB) ph1; split dump val u32 + idx u16 ph2.
__global__ __launch_bounds__(256) void k1_knn1_edge1(
    const float* __restrict__ x, const float* __restrict__ W1,
    const float* __restrict__ g1, const float* __restrict__ b1,
    const float* __restrict__ m1, const float* __restrict__ v1,
    float* __restrict__ x1, __bf16* __restrict__ x1h, __bf16* __restrict__ x1l,
    float* __restrict__ xx2)
{
  __shared__ __align__(16) char smemraw[35840];
  ull* pbuf = (ull*)smemraw;                   // [16][256]  (32 KB)   phase 1
  u32* dval = (u32*)smemraw;                   // [4][64][20] (20 KB)  phase 2
  u16* didx = (u16*)(smemraw + 20480);         // [4][64][20] (10 KB)
  u32* midx = (u32*)(smemraw + 30720);         // [64][20]    (5 KB)

  const int b = blockIdx.y;
  const int n0 = blockIdx.x * 64;
  const int tid = threadIdx.x;
  const int w = tid >> 6, L = tid & 63;
  const float* __restrict__ xr = x + (size_t)b*2*Np;
  const float* __restrict__ yr = xr + Np;

  const int n = n0 + L;
  const float px = xr[n], py = yr[n];

  ull kv[20];
#pragma unroll
  for (int s = 0; s < 20; ++s) kv[s] = 0ull;
  u32 u_cut = 0xFFFFFFFFu;
  int cnt = 0;

  auto flushK = [&]() {
#pragma unroll 1
    for (int f0 = 0; f0 < 16; f0 += 8) {
      if (__all(f0 >= cnt)) break;
      ull t0[8];
#pragma unroll
      for (int u = 0; u < 8; ++u) t0[u] = pbuf[(f0+u)*256 + tid];
#pragma unroll
      for (int u = 0; u < 8; ++u) {        // static t0 index only
        int f = f0 + u;
        ull key = t0[u];
        if (f < cnt && key > kv[19]) {
          ull ck = key;
#pragma unroll
          for (int s = 0; s < 20; ++s) {
            bool sw = ck > kv[s];
            ull tv = kv[s];
            kv[s] = sw ? ck : kv[s];
            ck = sw ? tv : ck;
          }
        }
      }
    }
    cnt = 0;
    u_cut = ~(u32)(kv[19] >> 32);
  };

  const int base = w * 1024;
  for (int j0 = base; j0 < base + 1024; j0 += 8) {
    float4 xv0 = *reinterpret_cast<const float4*>(xr + j0);      // uniform -> s_load
    float4 xv1 = *reinterpret_cast<const float4*>(xr + j0 + 4);
    float4 yv0 = *reinterpret_cast<const float4*>(yr + j0);
    float4 yv1 = *reinterpret_cast<const float4*>(yr + j0 + 4);
    const float xs[8] = {xv0.x, xv0.y, xv0.z, xv0.w, xv1.x, xv1.y, xv1.z, xv1.w};
    const float ys[8] = {yv0.x, yv0.y, yv0.z, yv0.w, yv1.x, yv1.y, yv1.z, yv1.w};
#pragma unroll
    for (int r = 0; r < 8; ++r) {
      float dx = xs[r] - px, dy = ys[r] - py;
      float s = dx*dx + dy*dy;
      u32 ub = __float_as_uint(s);
      if (ub <= u_cut) {
        int j = j0 + r;
        pbuf[cnt*256 + tid] = (((ull)~ub) << 32) | (u32)~(u32)j;
        ++cnt;
      }
    }
    if (__any(cnt >= 8)) flushK();   // cap 16: max cnt 7+8=15
  }
  flushK();

  __syncthreads();             // pbuf dead; switch to split dump layout
#pragma unroll
  for (int k = 0; k < Kn; ++k) {
    dval[((size_t)w*64 + L)*20 + k] = (u32)(kv[k] >> 32);
    didx[((size_t)w*64 + L)*20 + k] = (u16)(~(u32)kv[k]);   // = j exactly
  }
  __syncthreads();

  if (tid < 64) {
    const int p = tid;
    u32 hv[4], hx[4]; int pc[4];
#pragma unroll
    for (int q = 0; q < 4; ++q) {
      hv[q] = dval[((size_t)q*64 + p)*20];
      hx[q] = didx[((size_t)q*64 + p)*20];
      pc[q] = 0;
    }
#pragma unroll
    for (int k = 0; k < Kn; ++k) {
      u32 bv = hv[0], bx = hx[0]; int sel = 0;
      if (hv[1] > bv || (hv[1] == bv && hx[1] < bx)) { bv = hv[1]; bx = hx[1]; sel = 1; }
      if (hv[2] > bv || (hv[2] == bv && hx[2] < bx)) { bv = hv[2]; bx = hx[2]; sel = 2; }
      if (hv[3] > bv || (hv[3] == bv && hx[3] < bx)) { bv = hv[3]; bx = hx[3]; sel = 3; }
      midx[p*20 + k] = bx;
      int np_ = ++pc[sel];
      hv[sel] = (np_ < 20) ? dval[((size_t)sel*64 + p)*20 + np_] : 0u;
      hx[sel] = (np_ < 20) ? (u32)didx[((size_t)sel*64 + p)*20 + np_] : 0xFFFFu;
    }
  }
  __syncthreads();

  // phase 3: edgeconv1 — wave w handles points w*16..w*16+15, lane = channel o
  const int o = L;
  const float4 w1v = reinterpret_cast<const float4*>(W1)[o];
  const float sc = g1[o] / sqrtf(v1[o] + EPSf);
  const float mo = m1[o], bo = b1[o];

  for (int pi = 0; pi < 16; ++pi) {
    const int p = w*16 + pi;
    const int np = n0 + p;
    const float cx0 = xr[np], cx1 = yr[np];          // uniform
    const float cterm = (w1v.z - w1v.x)*cx0 + (w1v.w - w1v.y)*cx1;
    float xm = NEGINF;
#pragma unroll
    for (int k = 0; k < Kn; ++k) {
      int j = __builtin_amdgcn_readfirstlane(midx[p*20 + k]);
      float xj = xr[j], yj = yr[j];                  // s_loads
      float vv = w1v.x*xj + w1v.y*yj + cterm;
      float h = (vv - mo)*sc + bo;
      h = h >= 0.f ? h : SLOPE*h;
      xm = fmaxf(xm, h);
    }
    x1[(b*64 + o)*Np + np] = xm;
    __bf16 hb = (__bf16)xm;
    __bf16 lb = (__bf16)(xm - (float)hb);
    size_t tbase = ((size_t)b*Np + np)*64 + o;
    x1h[tbase] = hb;
    x1l[tbase] = lb;
    float s = xm*xm;
#pragma unroll
    for (int off = 1; off < 64; off <<= 1) s += __shfl_xor(s, off);
    if (L == 0) xx2[b*Np + np] = s;
  }
}

// ---------------- K2: knn2 — two-phase exact top-20, 25.8KB LDS (6 blocks/CU) ----------
// grid (256 rowblocks, B), 256 thr. Norms read straight from global (L1/L2-served).
__global__ __launch_bounds__(256) void k2_knn2(
    const __bf16* __restrict__ xh, const __bf16* __restrict__ xl,
    const float* __restrict__ xx2, int* __restrict__ idx2)
{
  __shared__ u32 smem[6448];           // 25.8 KB
  u32* pbuf    = smem;                 // [0,2560)    phase A push stacks [10][256]
  u32* dumpA   = smem;                 // [0,5120)    lane lists [4][64][20] (pbuf dead)
  u32* merged1 = smem + 5120;          // [5120,6400) stage-1 lists [4][16][20]
  u32* v20u    = smem + 6400;          // [6400,6416)
  u32* cntGT   = smem + 6416;          // [6416,6432)
  u32* cntEQ   = smem + 6432;          // [6432,6448)
  u32* jbuf    = smem;                 // [0,320)     phase B definite js [16][20]
  u32* tiebuf  = smem + 320;           // [320,832)   phase B tie js [16][32]

  const int b = blockIdx.y;
  const int n0 = blockIdx.x * 16;
  const int tid = threadIdx.x;
  const int w = tid >> 6, L = tid & 63;
  const int L15 = L & 15, quad = L >> 4;

  const float* __restrict__ xxb = xx2 + (size_t)b*Np;

  // B operand: rows n0..n0+15 (resident all kernel)
  const __bf16* Rh = xh + ((size_t)b*Np + n0)*64;
  const __bf16* Rl = xl + ((size_t)b*Np + n0)*64;
  bf16x8 rh0 = *reinterpret_cast<const bf16x8*>(Rh + L15*64 +  0 + quad*8);
  bf16x8 rh1 = *reinterpret_cast<const bf16x8*>(Rh + L15*64 + 32 + quad*8);
  bf16x8 rl0 = *reinterpret_cast<const bf16x8*>(Rl + L15*64 +  0 + quad*8);
  bf16x8 rl1 = *reinterpret_cast<const bf16x8*>(Rl + L15*64 + 32 + quad*8);

  const __bf16* Cbh = xh + (size_t)b*Np*64;
  const __bf16* Cbl = xl + (size_t)b*Np*64;

  u32 kv[20];
#pragma unroll
  for (int s = 0; s < 20; ++s) kv[s] = 0u;
  float fthresh = NEGINF;
  int cnt = 0;

  auto flush = [&]() {
#pragma unroll 1
    for (int f = 0; f < 10; ++f) {     // dynamic LDS addressing (no reg array)
      if (__all(f >= cnt)) break;
      u32 key = pbuf[f*256 + tid];
      if (f < cnt && key > kv[19]) {
        u32 ck = key;
#pragma unroll
        for (int s = 0; s < 20; ++s) {
          bool sw = ck > kv[s];
          u32 tv = kv[s];
          kv[s] = sw ? ck : kv[s];
          ck = sw ? tv : ck;
        }
      }
    }
    cnt = 0;
    u32 t = kv[19];
    u32 t2 = __shfl_xor(t, 16); t = t2 > t ? t2 : t;
    t2 = __shfl_xor(t, 32);     t = t2 > t ? t2 : t;
    if (t != 0u) {
      u32 uu = (t >> 31) ? (t ^ 0x80000000u) : ~t;   // exact unsort
      fthresh = __uint_as_float(uu);
    }
  };

  // ---- Phase A: exact per-lane top-20 values ----
  for (int t = 0; t < 16; ++t) {
    const int colbase = (w + t*4) * 64;
#pragma unroll
    for (int s = 0; s < 4; ++s) {
      const int col16 = colbase + s*16;
      const __bf16* ph = Cbh + (size_t)(col16 + L15)*64 + quad*8;
      const __bf16* pl = Cbl + (size_t)(col16 + L15)*64 + quad*8;
      bf16x8 a0 = *reinterpret_cast<const bf16x8*>(ph);
      bf16x8 a1 = *reinterpret_cast<const bf16x8*>(ph + 32);
      bf16x8 a2 = *reinterpret_cast<const bf16x8*>(pl);
      bf16x8 a3 = *reinterpret_cast<const bf16x8*>(pl + 32);
      f32x4 acc = (f32x4){0.f, 0.f, 0.f, 0.f};
      acc = __builtin_amdgcn_mfma_f32_16x16x32_bf16(a0, rh0, acc, 0, 0, 0);
      acc = __builtin_amdgcn_mfma_f32_16x16x32_bf16(a1, rh1, acc, 0, 0, 0);
      acc = __builtin_amdgcn_mfma_f32_16x16x32_bf16(a0, rl0, acc, 0, 0, 0);
      acc = __builtin_amdgcn_mfma_f32_16x16x32_bf16(a1, rl1, acc, 0, 0, 0);
      acc = __builtin_amdgcn_mfma_f32_16x16x32_bf16(a2, rh0, acc, 0, 0, 0);
      acc = __builtin_amdgcn_mfma_f32_16x16x32_bf16(a3, rh1, acc, 0, 0, 0);
      float4 xv = *reinterpret_cast<const float4*>(xxb + col16 + quad*4);
      const float xvr[4] = {xv.x, xv.y, xv.z, xv.w};
#pragma unroll
      for (int r = 0; r < 4; ++r) {
        float e = 2.0f*acc[r] - xvr[r];
        if (e >= fthresh) {
          u32 uu = __float_as_uint(e);
          u32 hk = uu ^ ((u32)((int)uu >> 31) | 0x80000000u);
          pbuf[cnt*256 + tid] = hk;
          ++cnt;
        }
      }
      if (__any(cnt >= 6)) flush();   // cap 10: max cnt 5+4=9
    }
  }
  flush();

  __syncthreads();   // pbuf dead -> dumpA
#pragma unroll
  for (int k = 0; k < Kn; ++k) dumpA[((size_t)w*64 + L)*20 + k] = kv[k];
  __syncthreads();

  // stage 1: 64 threads, (wave wv, row r16): 4-way value merge -> merged1
  if (tid < 64) {
    const int wv = tid >> 4, r16 = tid & 15;
    u32 h[4]; int pc[4];
#pragma unroll
    for (int q = 0; q < 4; ++q) { h[q] = dumpA[((size_t)wv*64 + q*16 + r16)*20]; pc[q] = 0; }
#pragma unroll
    for (int k = 0; k < Kn; ++k) {
      u32 best = h[0]; int sel = 0;
      if (h[1] > best) { best = h[1]; sel = 1; }
      if (h[2] > best) { best = h[2]; sel = 2; }
      if (h[3] > best) { best = h[3]; sel = 3; }
      merged1[((size_t)wv*16 + r16)*20 + k] = best;
      int np_ = ++pc[sel];
      h[sel] = (np_ < 20) ? dumpA[((size_t)wv*64 + sel*16 + r16)*20 + np_] : 0u;
    }
  }
  __syncthreads();

  // stage 2: 16 threads, row r: 4-way merge, keep only the 20th value; zero counters
  if (tid < 16) {
    const int r = tid;
    u32 h[4]; int pc[4];
#pragma unroll
    for (int q = 0; q < 4; ++q) { h[q] = merged1[((size_t)q*16 + r)*20]; pc[q] = 0; }
    u32 last = 0u;
#pragma unroll
    for (int k = 0; k < Kn; ++k) {
      u32 best = h[0]; int sel = 0;
      if (h[1] > best) { best = h[1]; sel = 1; }
      if (h[2] > best) { best = h[2]; sel = 2; }
      if (h[3] > best) { best = h[3]; sel = 3; }
      last = best;
      int np_ = ++pc[sel];
      h[sel] = (np_ < 20) ? merged1[((size_t)sel*16 + r)*20 + np_] : 0u;
    }
    v20u[r] = last;
    cntGT[r] = 0;
    cntEQ[r] = 0;
  }
  __syncthreads();

  // ---- Phase B: recompute (bitwise identical), collect indices ----
  for (int t = 0; t < 16; ++t) {
    const int colbase = (w + t*4) * 64;
#pragma unroll
    for (int s = 0; s < 4; ++s) {
      const int col16 = colbase + s*16;
      const __bf16* ph = Cbh + (size_t)(col16 + L15)*64 + quad*8;
      const __bf16* pl = Cbl + (size_t)(col16 + L15)*64 + quad*8;
      bf16x8 a0 = *reinterpret_cast<const bf16x8*>(ph);
      bf16x8 a1 = *reinterpret_cast<const bf16x8*>(ph + 32);
      bf16x8 a2 = *reinterpret_cast<const bf16x8*>(pl);
      bf16x8 a3 = *reinterpret_cast<const bf16x8*>(pl + 32);
      f32x4 acc = (f32x4){0.f, 0.f, 0.f, 0.f};
      acc = __builtin_amdgcn_mfma_f32_16x16x32_bf16(a0, rh0, acc, 0, 0, 0);
      acc = __builtin_amdgcn_mfma_f32_16x16x32_bf16(a1, rh1, acc, 0, 0, 0);
      acc = __builtin_amdgcn_mfma_f32_16x16x32_bf16(a0, rl0, acc, 0, 0, 0);
      acc = __builtin_amdgcn_mfma_f32_16x16x32_bf16(a1, rl1, acc, 0, 0, 0);
      acc = __builtin_amdgcn_mfma_f32_16x16x32_bf16(a2, rh0, acc, 0, 0, 0);
      acc = __builtin_amdgcn_mfma_f32_16x16x32_bf16(a3, rh1, acc, 0, 0, 0);
      float4 xv = *reinterpret_cast<const float4*>(xxb + col16 + quad*4);
      const float xvr[4] = {xv.x, xv.y, xv.z, xv.w};
      const u32 vt = v20u[L15];
#pragma unroll
      for (int r = 0; r < 4; ++r) {
        float e = 2.0f*acc[r] - xvr[r];
        u32 uu = __float_as_uint(e);
        u32 se = uu ^ ((u32)((int)uu >> 31) | 0x80000000u);
        if (se >= vt) {
          int j = col16 + quad*4 + r;
          if (se > vt) {
            u32 pos = atomicAdd(&cntGT[L15], 1u);
            if (pos < 20u) jbuf[L15*20 + pos] = (u32)j;
          } else {
            u32 pos = atomicAdd(&cntEQ[L15], 1u);
            if (pos < 32u) tiebuf[L15*32 + pos] = (u32)j;
          }
        }
      }
    }
  }
  __syncthreads();

  // finalize: 16 threads/row — definite js + lowest-j ties to fill 20
  if (tid < 16) {
    const int r = tid;
    int ngt = (int)cntGT[r]; ngt = ngt > 20 ? 20 : ngt;   // math guarantees <=19
    int neq = (int)cntEQ[r]; neq = neq > 32 ? 32 : neq;
    size_t obase = ((size_t)b*Np + n0 + r)*Kn;
#pragma unroll 1
    for (int k = 0; k < ngt; ++k) idx2[obase + k] = (int)jbuf[r*20 + k];
    int need = Kn - ngt;
#pragma unroll 1
    for (int k = 0; k < need; ++k) {
      u32 best = 0xFFFFFFFFu; int bi = -1;
#pragma unroll 1
      for (int i = 0; i < neq; ++i) {
        u32 v = tiebuf[r*32 + i];
        if (v < best) { best = v; bi = i; }
      }
      if (bi >= 0) tiebuf[r*32 + bi] = 0xFFFFFFFFu;
      idx2[obase + ngt + k] = (bi >= 0) ? (int)best : 0;
    }
  }
}

// ---------------- K3a: Y = W2a * x1 (column-major out), W2a staged in LDS ----------------
__global__ __launch_bounds__(256) void k3a_Y(
    const __bf16* __restrict__ xh, const __bf16* __restrict__ xl,
    const float* __restrict__ W2, float* __restrict__ Ycol)
{
  __shared__ float w2s[64][65];
  __shared__ float xs[4][16][65];
  const int b = blockIdx.y;
  const int tid = threadIdx.x;
  const int w = tid >> 6, L = tid & 63;

  for (int i = tid; i < 4096; i += 256) {
    int o = i >> 6, c = i & 63;
    w2s[o][c] = W2[o*128 + c];
  }
  __syncthreads();

  const int p0 = blockIdx.x*64 + w*16;
  for (int i = 0; i < 16; ++i) {
    size_t base = ((size_t)b*Np + p0 + i)*64 + L;
    xs[w][i][L] = (float)xh[base] + (float)xl[base];
  }
  for (int i = 0; i < 16; ++i) {
    float y = 0.f;
#pragma unroll
    for (int c = 0; c < 64; ++c)
      y += w2s[L][c] * xs[w][i][c];
    Ycol[((size_t)b*Np + p0 + i)*64 + L] = y;
  }
}

// ---------------- K3b: edgeconv2 gather — x2[o][n] = max_k lrelu(bn(Y[:,jk] + Z[:,n])) ---
__global__ __launch_bounds__(256) void k3b_edge2(
    const __bf16* __restrict__ xh, const __bf16* __restrict__ xl,
    const float* __restrict__ W2, const int* __restrict__ idx2,
    const float* __restrict__ Ycol,
    const float* __restrict__ g2, const float* __restrict__ b2,
    const float* __restrict__ m2, const float* __restrict__ v2,
    float* __restrict__ x2)
{
  __shared__ float w2d[64][65];
  __shared__ float xs[4][16][65];
  const int b = blockIdx.y;
  const int tid = threadIdx.x;
  const int w = tid >> 6, L = tid & 63;

  for (int i = tid; i < 4096; i += 256) {
    int o = i >> 6, c = i & 63;
    w2d[o][c] = W2[o*128 + 64 + c] - W2[o*128 + c];
  }
  __syncthreads();

  const float sc2 = g2[L]/sqrtf(v2[L]+EPSf);
  const float m2o = m2[L], b2o = b2[L];

  const int p0 = blockIdx.x*64 + w*16;
  for (int i = 0; i < 16; ++i) {
    size_t base = ((size_t)b*Np + p0 + i)*64 + L;
    xs[w][i][L] = (float)xh[base] + (float)xl[base];
  }
  for (int i = 0; i < 16; ++i) {
    const int n = p0 + i;
    float z = 0.f;
#pragma unroll
    for (int c = 0; c < 64; ++c)
      z += w2d[L][c] * xs[w][i][c];
    const int* ip = idx2 + ((size_t)b*Np + n)*Kn;   // uniform -> s_loads
    float xm = NEGINF;
#pragma unroll
    for (int k = 0; k < Kn; ++k) {
      int j = ip[k];
      float yv = Ycol[((size_t)b*Np + j)*64 + L];   // coalesced 256B column
      float vv = yv + z;
      float hh = (vv - m2o)*sc2 + b2o;
      hh = hh >= 0.f ? hh : SLOPE*hh;
      xm = fmaxf(xm, hh);
    }
    x2[(b*64 + L)*Np + n] = xm;
  }
}

// ---------------- K4: conv5 + per-block max, two 64-channel passes ----------------
__global__ __launch_bounds__(256) void k4_conv5max(
    const float* __restrict__ x1, const float* __restrict__ x2,
    const float* __restrict__ W5,
    const float* __restrict__ g5, const float* __restrict__ b5,
    const float* __restrict__ m5, const float* __restrict__ v5,
    float* __restrict__ partials)  // (B,128,64)
{
  const int b = blockIdx.y, nb = blockIdx.x;
  const int tid = threadIdx.x;
  const int p = tid & 63;
  const int g = __builtin_amdgcn_readfirstlane(tid >> 6);
  const int n = nb*64 + p;

  float xcr[64], dotp[32];
#pragma unroll
  for (int c = 0; c < 64; ++c) xcr[c] = x1[(b*64 + c)*Np + n];
#pragma unroll
  for (int oi = 0; oi < 32; ++oi) {
    const float* wr = W5 + (g*32 + oi)*128;
    float d = 0.f;
#pragma unroll
    for (int c = 0; c < 64; c += 4) {
      float4 wv = *reinterpret_cast<const float4*>(wr + c);
      d += wv.x*xcr[c] + wv.y*xcr[c+1] + wv.z*xcr[c+2] + wv.w*xcr[c+3];
    }
    dotp[oi] = d;
  }
#pragma unroll
  for (int c = 0; c < 64; ++c) xcr[c] = x2[(b*64 + c)*Np + n];
#pragma unroll
  for (int oi = 0; oi < 32; ++oi) {
    const int o = g*32 + oi;
    const float* wr = W5 + o*128 + 64;
    float d = dotp[oi];
#pragma unroll
    for (int c = 0; c < 64; c += 4) {
      float4 wv = *reinterpret_cast<const float4*>(wr + c);
      d += wv.x*xcr[c] + wv.y*xcr[c+1] + wv.z*xcr[c+2] + wv.w*xcr[c+3];
    }
    float hv = (d - m5[o])*(g5[o]/sqrtf(v5[o]+EPSf)) + b5[o];
    hv = hv >= 0.f ? hv : SLOPE*hv;
#pragma unroll
    for (int off = 1; off < 64; off <<= 1) hv = fmaxf(hv, __shfl_xor(hv, off));
    if (p == 0) partials[(b*128 + o)*64 + nb] = hv;
  }
}

// ---------------- K5: reduce partial maxima -> gmax, then t6 = W6a * gmax ----------------
__global__ __launch_bounds__(256) void k5_reduce_t6(
    const float* __restrict__ partials, const float* __restrict__ W6,
    float* __restrict__ t6)  // (B,256)
{
  __shared__ float sg[128];
  const int b = blockIdx.x;
  const int tid = threadIdx.x;
  if (tid < 128) {
    float m = NEGINF;
    for (int w = 0; w < 64; ++w) m = fmaxf(m, partials[(b*128 + tid)*64 + w]);
    sg[tid] = m;
  }
  __syncthreads();
  float a = 0.f;
#pragma unroll
  for (int c = 0; c < 128; c += 4) {
    float4 wv = *reinterpret_cast<const float4*>(W6 + tid*256 + c);
    a += wv.x*sg[c] + wv.y*sg[c+1] + wv.z*sg[c+2] + wv.w*sg[c+3];
  }
  t6[b*256 + tid] = a;
}

// ---------------- K6: conv6 + W9, two o-groups x two channel passes ----------------
__global__ __launch_bounds__(256) void k6_conv6_out(
    const float* __restrict__ x1, const float* __restrict__ x2,
    const float* __restrict__ W6, const float* __restrict__ t6,
    const float* __restrict__ g6, const float* __restrict__ b6,
    const float* __restrict__ m6, const float* __restrict__ v6,
    const float* __restrict__ W9,
    float* __restrict__ out)
{
  __shared__ float red[4][64];
  const int b = blockIdx.y, nb = blockIdx.x;
  const int tid = threadIdx.x;
  const int p = tid & 63;
  const int g = __builtin_amdgcn_readfirstlane(tid >> 6);
  const int n = nb*64 + p;

  float oacc = 0.f;
#pragma unroll
  for (int oh = 0; oh < 2; ++oh) {
    float xcr[64], dotp[32];
#pragma unroll
    for (int c = 0; c < 64; ++c) xcr[c] = x1[(b*64 + c)*Np + n];
#pragma unroll
    for (int oi = 0; oi < 32; ++oi) {
      const int o = g*64 + oh*32 + oi;
      const float* wr = W6 + o*256 + 128;
      float d = t6[b*256 + o];
#pragma unroll
      for (int c = 0; c < 64; c += 4) {
        float4 wv = *reinterpret_cast<const float4*>(wr + c);
        d += wv.x*xcr[c] + wv.y*xcr[c+1] + wv.z*xcr[c+2] + wv.w*xcr[c+3];
      }
      dotp[oi] = d;
    }
#pragma unroll
    for (int c = 0; c < 64; ++c) xcr[c] = x2[(b*64 + c)*Np + n];
#pragma unroll
    for (int oi = 0; oi < 32; ++oi) {
      const int o = g*64 + oh*32 + oi;
      const float* wr = W6 + o*256 + 192;
      float d = dotp[oi];
#pragma unroll
      for (int c = 0; c < 64; c += 4) {
        float4 wv = *reinterpret_cast<const float4*>(wr + c);
        d += wv.x*xcr[c] + wv.y*xcr[c+1] + wv.z*xcr[c+2] + wv.w*xcr[c+3];
      }
      float hv = (d - m6[o])*(g6[o]/sqrtf(v6[o]+EPSf)) + b6[o];
      hv = hv >= 0.f ? hv : SLOPE*hv;
      oacc += W9[o]*hv;
    }
  }
  red[g][p] = oacc;
  __syncthreads();
  if (tid < 64)
    out[b*Np + nb*64 + tid] = red[0][tid] + red[1][tid] + red[2][tid] + red[3][tid];
}

extern "C" void kernel_launch(void* const* d_in, const int* in_sizes, int n_in,
                              void* d_out, int out_size, void* d_ws, size_t ws_size,
                              hipStream_t stream) {
  const float* x  = (const float*)d_in[0];
  const float* W1 = (const float*)d_in[1];
  const float* g1 = (const float*)d_in[2];
  const float* b1 = (const float*)d_in[3];
  const float* m1 = (const float*)d_in[4];
  const float* v1 = (const float*)d_in[5];
  const float* W2 = (const float*)d_in[6];
  const float* g2 = (const float*)d_in[7];
  const float* b2 = (const float*)d_in[8];
  const float* m2 = (const float*)d_in[9];
  const float* v2 = (const float*)d_in[10];
  const float* W5 = (const float*)d_in[11];
  const float* g5 = (const float*)d_in[12];
  const float* b5 = (const float*)d_in[13];
  const float* m5 = (const float*)d_in[14];
  const float* v5 = (const float*)d_in[15];
  const float* W6 = (const float*)d_in[16];
  const float* g6 = (const float*)d_in[17];
  const float* b6 = (const float*)d_in[18];
  const float* m6 = (const float*)d_in[19];
  const float* v6 = (const float*)d_in[20];
  const float* W9 = (const float*)d_in[21];
  float* out = (float*)d_out;

  float* F = (float*)d_ws;
  float*  x1    = F;                         // 1048576
  float*  xx2   = F + 1048576;               // 16384
  __bf16* x1h   = (__bf16*)(F + 1064960);    // 524288 float-slots
  __bf16* x1l   = (__bf16*)(F + 1589248);    // 524288
  float*  x2    = F + 2113536;               // 1048576
  float*  Ycol  = F + 3162112;               // 1048576
  int*    idx2  = (int*)(F + 4210688);       // 327680
  float*  t6    = F + 4538368;               // 1024
  float*  parts = F + 4539392;               // 32768

  k1_knn1_edge1<<<dim3(64,4), 256, 0, stream>>>(x, W1, g1, b1, m1, v1, x1, x1h, x1l, xx2);
  k2_knn2<<<dim3(256,4), 256, 0, stream>>>(x1h, x1l, xx2, idx2);
  k3a_Y<<<dim3(64,4), 256, 0, stream>>>(x1h, x1l, W2, Ycol);
  k3b_edge2<<<dim3(64,4), 256, 0, stream>>>(x1h, x1l, W2, idx2, Ycol, g2, b2, m2, v2, x2);
  k4_conv5max<<<dim3(64,4), 256, 0, stream>>>(x1, x2, W5, g5, b5, m5, v5, parts);
  k5_reduce_t6<<<4, 256, 0, stream>>>(parts, W6, t6);
  k6_conv6_out<<<dim3(64,4), 256, 0, stream>>>(x1, x2, W6, t6, g6, b6, m6, v6, W9, out);
}